// Round 4
// baseline (841.364 us; speedup 1.0000x reference)
//
#include <hip/hip_runtime.h>
#include <hip/hip_bf16.h>

typedef __hip_bfloat16 bf16;

// Problem constants
#define BB    4
#define LQ    4096
#define LIN   16464
#define DM    768
#define NH    12
#define HD    64
#define K_DIM 768
// Levels: (112,112),(56,56),(28,28); starts 0,12544,15680; query grid 64x64

typedef __attribute__((ext_vector_type(8))) __bf16 bfrag;
typedef __attribute__((ext_vector_type(4))) float  ffrag;

// ---------------------------------------------------------------------------
// async global->LDS 16B per lane (per-lane global src; LDS dest lane-contig)
// ---------------------------------------------------------------------------
__device__ __forceinline__ void g2l16(const void* g, void* l) {
    __builtin_amdgcn_global_load_lds(
        (const __attribute__((address_space(1))) void*)g,
        (__attribute__((address_space(3))) void*)l, 16, 0, 0);
}

// ---------------------------------------------------------------------------
// LayerNorm over last dim 768, fp32 in -> bf16 out. 192 threads, float4.
// ---------------------------------------------------------------------------
__global__ __launch_bounds__(192) void ln_kernel(
    const float* __restrict__ x, const float* __restrict__ g,
    const float* __restrict__ beta, bf16* __restrict__ y)
{
    int r = blockIdx.x;
    int t = threadIdx.x;
    float4 v = ((const float4*)(x + (size_t)r * DM))[t];
    float s  = v.x + v.y + v.z + v.w;
    float ss = v.x * v.x + v.y * v.y + v.z * v.z + v.w * v.w;
    #pragma unroll
    for (int o = 32; o > 0; o >>= 1) {
        s  += __shfl_down(s, o);
        ss += __shfl_down(ss, o);
    }
    __shared__ float sh1[3], sh2[3];
    int w = t >> 6, lane = t & 63;
    if (lane == 0) { sh1[w] = s; sh2[w] = ss; }
    __syncthreads();
    if (t == 0) {
        float a = sh1[0] + sh1[1] + sh1[2];
        float b = sh2[0] + sh2[1] + sh2[2];
        float mean = a * (1.f / DM);
        float var  = b * (1.f / DM) - mean * mean;
        sh1[0] = mean;
        sh2[0] = rsqrtf(var + 1e-6f);
    }
    __syncthreads();
    float mean = sh1[0], inv = sh2[0];
    float4 gg = ((const float4*)g)[t];
    float4 bb = ((const float4*)beta)[t];
    union { bf16 h[4]; uint2 u; } p;
    p.h[0] = __float2bfloat16((v.x - mean) * inv * gg.x + bb.x);
    p.h[1] = __float2bfloat16((v.y - mean) * inv * gg.y + bb.y);
    p.h[2] = __float2bfloat16((v.z - mean) * inv * gg.z + bb.z);
    p.h[3] = __float2bfloat16((v.w - mean) * inv * gg.w + bb.w);
    *(uint2*)(y + (size_t)r * DM + t * 4) = p.u;
}

// ---------------------------------------------------------------------------
// Cast + transpose weights: W (768 x N f32, row-major) -> Wt (gridX*32 x 768 bf16)
// rows n >= N zero-filled. Grid: (rows/32, 768/32), block 256.
// ---------------------------------------------------------------------------
__global__ __launch_bounds__(256) void cast_transpose(
    const float* __restrict__ W, bf16* __restrict__ Wt, int N)
{
    __shared__ float t[32][33];
    int n0 = blockIdx.x * 32, k0 = blockIdx.y * 32;
    int tx = threadIdx.x & 31, ty = threadIdx.x >> 5;  // ty 0..7
    #pragma unroll
    for (int i = 0; i < 4; i++) {
        int k = k0 + ty + i * 8;
        int n = n0 + tx;
        t[ty + i * 8][tx] = (n < N) ? W[(size_t)k * N + n] : 0.f;
    }
    __syncthreads();
    #pragma unroll
    for (int i = 0; i < 4; i++) {
        int n = n0 + ty + i * 8;
        Wt[(size_t)n * K_DIM + k0 + tx] = __float2bfloat16(t[tx][ty + i * 8]);
    }
}

// ---------------------------------------------------------------------------
// MFMA bf16 GEMM: C(M,N) = A(M,768) @ Wt(N,768)^T + bias
// 64x128 block tile, 256 threads (4 waves, wave-tile 32x64), K-step 32.
// LDS rows padded to 80 B (4 data chunks + 1 dup chunk) -> conflict-free reads.
// mode 0: bf16 store; mode 1: f32 store; mode 2: f32 = resid + gamma*(acc+bias)
// mode 3: f32 store, dual bias split at nsplit
// ---------------------------------------------------------------------------
#define ASTRIDE 80
__global__ __launch_bounds__(256) void mfma_gemm(
    const bf16*  __restrict__ A,
    const bf16*  __restrict__ Bt,
    const float* __restrict__ bias,
    void*        __restrict__ C,
    const float* __restrict__ resid,
    const float* __restrict__ gamma,
    const float* __restrict__ bias2,
    int M, int N, int mode, int nsplit)
{
    __shared__ __align__(16) char lds[15360];
    char* As = lds;            // 64 rows x 80 B = 5120
    char* Bs = lds + 5120;     // 128 rows x 80 B = 10240

    int tid  = threadIdx.x;
    int lane = tid & 63;
    int bm = blockIdx.y * 64, bn = blockIdx.x * 128;
    int wave = tid >> 6;
    int wr = (wave & 1) * 32, wc = (wave >> 1) * 64;

    ffrag acc[2][4] = {};

    // staging: A = 320 chunks (64 rows x 5), B = 640 chunks (128 rows x 5)
    // chunk c: row = c/5, cc = c%5 (cc==4 is pad -> duplicate cc=0 source)
    int cA0 = tid,        cA1 = tid + 256;           // cA1 valid if tid < 64
    int cB0 = tid,        cB1 = tid + 256, cB2 = tid + 512; // cB2 if tid < 128
    int rA0 = cA0 / 5, eA0 = (cA0 % 5) & 3;
    int rA1 = cA1 / 5, eA1 = (cA1 % 5) & 3;
    int rB0 = cB0 / 5, eB0 = (cB0 % 5) & 3;
    int rB1 = cB1 / 5, eB1 = (cB1 % 5) & 3;
    int rB2 = cB2 / 5, eB2 = (cB2 % 5) & 3;
    const bf16* gA0 = A  + (size_t)min(bm + rA0, M - 1) * K_DIM + eA0 * 8;
    const bf16* gA1 = A  + (size_t)min(bm + rA1, M - 1) * K_DIM + eA1 * 8;
    const bf16* gB0 = Bt + (size_t)(bn + rB0) * K_DIM + eB0 * 8;
    const bf16* gB1 = Bt + (size_t)(bn + rB1) * K_DIM + eB1 * 8;
    const bf16* gB2 = Bt + (size_t)(bn + min(rB2, 127)) * K_DIM + eB2 * 8;
    char* dA0 = As + cA0 * 16;
    char* dA1 = As + cA1 * 16;
    char* dB0 = Bs + cB0 * 16;
    char* dB1 = Bs + cB1 * 16;
    char* dB2 = Bs + cB2 * 16;
    bool pA1 = (tid < 64), pB2 = (tid < 128);

    int mrow = lane & 15;
    int kqb  = (lane >> 4) * 16;   // byte offset of K-octet

    for (int k0 = 0; k0 < K_DIM; k0 += 32) {
        g2l16(gA0 + k0, dA0);
        if (pA1) g2l16(gA1 + k0, dA1);
        g2l16(gB0 + k0, dB0);
        g2l16(gB1 + k0, dB1);
        if (pB2) g2l16(gB2 + k0, dB2);
        __syncthreads();
        bfrag a[2], b[4];
        #pragma unroll
        for (int t = 0; t < 2; t++)
            a[t] = *(const bfrag*)(As + (wr + t * 16 + mrow) * ASTRIDE + kqb);
        #pragma unroll
        for (int t = 0; t < 4; t++)
            b[t] = *(const bfrag*)(Bs + (wc + t * 16 + mrow) * ASTRIDE + kqb);
        #pragma unroll
        for (int i = 0; i < 2; i++)
            #pragma unroll
            for (int j = 0; j < 4; j++)
                acc[i][j] = __builtin_amdgcn_mfma_f32_16x16x32_bf16(
                    a[i], b[j], acc[i][j], 0, 0, 0);
        __syncthreads();
    }

    // epilogue: C/D layout col = lane&15, row = (lane>>4)*4 + reg
    int q4 = (lane >> 4) * 4;
    #pragma unroll
    for (int i = 0; i < 2; i++) {
        #pragma unroll
        for (int r = 0; r < 4; r++) {
            int rg = bm + wr + i * 16 + q4 + r;
            if (rg < M) {
                #pragma unroll
                for (int j = 0; j < 4; j++) {
                    int cg = bn + wc + j * 16 + mrow;
                    if (cg < N) {
                        float bv = (mode == 3 && cg >= nsplit) ? bias2[cg - nsplit]
                                                               : bias[cg];
                        float v = acc[i][j][r] + bv;
                        size_t idx = (size_t)rg * N + cg;
                        if (mode == 0)      ((bf16*)C)[idx]  = __float2bfloat16(v);
                        else if (mode == 2) ((float*)C)[idx] = resid[idx] + gamma[cg] * v;
                        else                ((float*)C)[idx] = v;
                    }
                }
            }
        }
    }
}

// ---------------------------------------------------------------------------
// Deformable sampling, corner-parallel:
// one wave per (b,q,h) unit; lane = corner-slot (lane>>3) x channel-octet (lane&7).
// comb (B*LQ, 432) f32: cols 0..287 = offsets, 288..431 = logits.
// ---------------------------------------------------------------------------
__global__ __launch_bounds__(256) void sample_kernel(
    const bf16*  __restrict__ value,
    const float* __restrict__ comb,
    bf16*        __restrict__ attn)
{
    int unit = __builtin_amdgcn_readfirstlane((blockIdx.x << 2) + (threadIdx.x >> 6));
    int lane = threadIdx.x & 63;
    int o   = lane & 7;          // channel octet -> channels o*8..o*8+7
    int c8  = lane >> 3;         // corner slot 0..7
    int k   = c8 & 3;
    int dx  = k & 1, dy = k >> 1;
    int h  = unit % NH;
    int bq = unit / NH;
    int q  = bq & (LQ - 1);
    int b  = bq >> 12;

    const float* rowp = comb + (size_t)bq * 432;
    const float* ob = rowp + h * 24;
    const float* lg = rowp + 288 + h * 12;

    float l[12];
    float mx = -1e30f;
    #pragma unroll
    for (int i = 0; i < 12; i++) { l[i] = lg[i]; mx = fmaxf(mx, l[i]); }
    float den = 0.f;
    #pragma unroll
    for (int i = 0; i < 12; i++) { l[i] = __expf(l[i] - mx); den += l[i]; }
    float rden = 1.f / den;
    #pragma unroll
    for (int i = 0; i < 12; i++) l[i] *= rden;

    float rx = ((q & 63) + 0.5f) * (1.f / 64.f);
    float ry = ((q >> 6) + 0.5f) * (1.f / 64.f);

    float acc[8] = {0.f};

    #pragma unroll
    for (int it = 0; it < 6; it++) {
        const int wl = (it < 2) ? 112 : (it < 4 ? 56 : 28);
        const int sl = (it < 2) ? 0   : (it < 4 ? 12544 : 15680);
        int s = it * 2 + ((lane >> 5) & 1);
        float ox = ob[s * 2 + 0];
        float oy = ob[s * 2 + 1];
        float x = rx * wl + ox - 0.5f;
        float y = ry * wl + oy - 0.5f;
        float xf = floorf(x), yf = floorf(y);
        float wx = x - xf,  wy = y - yf;
        int xi = (int)xf + dx;
        int yi = (int)yf + dy;
        bool valid = ((unsigned)xi < (unsigned)wl) & ((unsigned)yi < (unsigned)wl);
        int xc = min(max(xi, 0), wl - 1);
        int yc = min(max(yi, 0), wl - 1);
        int cell = b * LIN + sl + yc * wl + xc;
        const uint4* vp = (const uint4*)(value + ((size_t)cell * NH + h) * HD + o * 8);
        uint4 v = *vp;
        float aw = (lane & 32) ? l[it * 2 + 1] : l[it * 2];
        float bw = (dx ? wx : 1.f - wx) * (dy ? wy : 1.f - wy);
        float w = valid ? aw * bw : 0.f;
        const unsigned* u = (const unsigned*)&v;
        #pragma unroll
        for (int j = 0; j < 4; j++) {
            float f0 = __uint_as_float(u[j] << 16);
            float f1 = __uint_as_float(u[j] & 0xFFFF0000u);
            acc[j * 2 + 0] = fmaf(w, f0, acc[j * 2 + 0]);
            acc[j * 2 + 1] = fmaf(w, f1, acc[j * 2 + 1]);
        }
    }

    #pragma unroll
    for (int m = 8; m <= 32; m <<= 1) {
        #pragma unroll
        for (int j = 0; j < 8; j++)
            acc[j] += __shfl_xor(acc[j], m);
    }

    if (c8 == 0) {
        union { bf16 h8[8]; uint4 u4; } r;
        #pragma unroll
        for (int j = 0; j < 8; j++) r.h8[j] = __float2bfloat16(acc[j]);
        *(uint4*)(attn + (size_t)bq * DM + h * HD + o * 8) = r.u4;
    }
}

// ---------------------------------------------------------------------------
extern "C" void kernel_launch(void* const* d_in, const int* in_sizes, int n_in,
                              void* d_out, int out_size, void* d_ws, size_t ws_size,
                              hipStream_t stream)
{
    const float* query  = (const float*)d_in[0];
    const float* feat   = (const float*)d_in[1];
    const float* ln_q_g = (const float*)d_in[2];
    const float* ln_q_b = (const float*)d_in[3];
    const float* ln_f_g = (const float*)d_in[4];
    const float* ln_f_b = (const float*)d_in[5];
    const float* W_off  = (const float*)d_in[6];
    const float* b_off  = (const float*)d_in[7];
    const float* W_attn = (const float*)d_in[8];
    const float* b_attn = (const float*)d_in[9];
    const float* W_val  = (const float*)d_in[10];
    const float* b_val  = (const float*)d_in[11];
    const float* W_out  = (const float*)d_in[12];
    const float* b_out  = (const float*)d_in[13];
    const float* gamma  = (const float*)d_in[14];
    float* out = (float*)d_out;

    char* ws = (char*)d_ws;
    char* od = (char*)d_out;
    const int M_F = BB * LIN;   // 65856
    const int M_Q = BB * LQ;    // 16384

    // ws layout (227,475,456 B proven):
    bf16*  value  = (bf16*)(ws);
    bf16*  f_ln   = (bf16*)(ws + 101154816);
    bf16*  Wt_out = (bf16*)(ws + 101154816);
    bf16*  q_ln   = (bf16*)(ws + 202309632);
    bf16*  attn   = (bf16*)(ws + 202309632);

    // d_out as scratch (dead before final GEMM):
    bf16*  Wt_val  = (bf16*)(od);
    bf16*  Wt_comb = (bf16*)(od + 1179648);
    float* comb    = (float*)(od + 2162688);

    // 1. weight cast/transpose
    cast_transpose<<<dim3(24, 24), 256, 0, stream>>>(W_val, Wt_val, 768);
    cast_transpose<<<dim3(9, 24), 256, 0, stream>>>(W_off, Wt_comb, 288);
    cast_transpose<<<dim3(7, 24), 256, 0, stream>>>(
        W_attn, Wt_comb + (size_t)288 * K_DIM, 144);

    // 2. LayerNorms
    ln_kernel<<<M_F, 192, 0, stream>>>(feat, ln_f_g, ln_f_b, f_ln);
    ln_kernel<<<M_Q, 192, 0, stream>>>(query, ln_q_g, ln_q_b, q_ln);

    // 3. value = f_ln @ W_val + b_val (bf16)
    mfma_gemm<<<dim3(6, M_F / 64), 256, 0, stream>>>(
        f_ln, Wt_val, b_val, value, nullptr, nullptr, nullptr, M_F, DM, 0, 0);

    // 4. Wt_out into f_ln's (now dead) region
    cast_transpose<<<dim3(24, 24), 256, 0, stream>>>(W_out, Wt_out, 768);

    // 5. comb = q_ln @ [W_off | W_attn] + [b_off | b_attn] (f32, N=432)
    mfma_gemm<<<dim3(4, M_Q / 64), 256, 0, stream>>>(
        q_ln, Wt_comb, b_off, comb, nullptr, nullptr, b_attn, M_Q, 432, 3, 288);

    // 6. deformable sampling -> attn (bf16)
    sample_kernel<<<(M_Q * NH) / 4, 256, 0, stream>>>(value, comb, attn);

    // 7. out = query + gamma * (attn @ W_out + b_out)
    mfma_gemm<<<dim3(6, M_Q / 64), 256, 0, stream>>>(
        attn, Wt_out, b_out, out, query, gamma, nullptr, M_Q, DM, 2, 0);
}

// Round 5
// 802.159 us; speedup vs baseline: 1.0489x; 1.0489x over previous
//
#include <hip/hip_runtime.h>
#include <hip/hip_bf16.h>

typedef __hip_bfloat16 bf16;

// Problem constants
#define BB    4
#define LQ    4096
#define LIN   16464
#define DM    768
#define NH    12
#define HD    64
#define K_DIM 768
// Levels: (112,112),(56,56),(28,28); starts 0,12544,15680; query grid 64x64

typedef __attribute__((ext_vector_type(8))) __bf16 bfrag;
typedef __attribute__((ext_vector_type(4))) float  ffrag;

// ---------------------------------------------------------------------------
// async global->LDS 16B per lane (LDS dest is wave-uniform base + lane*16)
// ---------------------------------------------------------------------------
__device__ __forceinline__ void g2l16(const void* g, void* l) {
    __builtin_amdgcn_global_load_lds(
        (const __attribute__((address_space(1))) void*)g,
        (__attribute__((address_space(3))) void*)l, 16, 0, 0);
}

// ---------------------------------------------------------------------------
// LayerNorm over last dim 768: one wave per row, 4 rows/block.
// Pure shfl_xor reduction — no LDS, no barrier.
// ---------------------------------------------------------------------------
__global__ __launch_bounds__(256) void ln_kernel(
    const float* __restrict__ x, const float* __restrict__ g,
    const float* __restrict__ beta, bf16* __restrict__ y)
{
    int r = blockIdx.x * 4 + (threadIdx.x >> 6);
    int lane = threadIdx.x & 63;
    const float4* xr = (const float4*)(x + (size_t)r * DM);
    float4 v[3];
    #pragma unroll
    for (int i = 0; i < 3; i++) v[i] = xr[lane + 64 * i];
    float s = 0.f, ss = 0.f;
    #pragma unroll
    for (int i = 0; i < 3; i++) {
        s  += v[i].x + v[i].y + v[i].z + v[i].w;
        ss += v[i].x * v[i].x + v[i].y * v[i].y + v[i].z * v[i].z + v[i].w * v[i].w;
    }
    #pragma unroll
    for (int m = 1; m <= 32; m <<= 1) {
        s  += __shfl_xor(s, m);
        ss += __shfl_xor(ss, m);
    }
    float mean = s * (1.f / DM);
    float inv  = rsqrtf(ss * (1.f / DM) - mean * mean + 1e-6f);
    bf16* yr = y + (size_t)r * DM;
    #pragma unroll
    for (int i = 0; i < 3; i++) {
        float4 gg = ((const float4*)g)[lane + 64 * i];
        float4 bb = ((const float4*)beta)[lane + 64 * i];
        union { bf16 h[4]; uint2 u; } p;
        p.h[0] = __float2bfloat16((v[i].x - mean) * inv * gg.x + bb.x);
        p.h[1] = __float2bfloat16((v[i].y - mean) * inv * gg.y + bb.y);
        p.h[2] = __float2bfloat16((v[i].z - mean) * inv * gg.z + bb.z);
        p.h[3] = __float2bfloat16((v[i].w - mean) * inv * gg.w + bb.w);
        *(uint2*)(yr + (lane + 64 * i) * 4) = p.u;
    }
}

// ---------------------------------------------------------------------------
// Cast + transpose weights: W (768 x N f32, row-major) -> Wt (gridX*32 x 768 bf16)
// rows n >= N zero-filled. Grid: (rows/32, 768/32), block 256.
// ---------------------------------------------------------------------------
__global__ __launch_bounds__(256) void cast_transpose(
    const float* __restrict__ W, bf16* __restrict__ Wt, int N)
{
    __shared__ float t[32][33];
    int n0 = blockIdx.x * 32, k0 = blockIdx.y * 32;
    int tx = threadIdx.x & 31, ty = threadIdx.x >> 5;  // ty 0..7
    #pragma unroll
    for (int i = 0; i < 4; i++) {
        int k = k0 + ty + i * 8;
        int n = n0 + tx;
        t[ty + i * 8][tx] = (n < N) ? W[(size_t)k * N + n] : 0.f;
    }
    __syncthreads();
    #pragma unroll
    for (int i = 0; i < 4; i++) {
        int n = n0 + ty + i * 8;
        Wt[(size_t)n * K_DIM + k0 + tx] = __float2bfloat16(t[tx][ty + i * 8]);
    }
}

// ---------------------------------------------------------------------------
// MFMA bf16 GEMM: C(M,N) = A(M,768) @ Wt(N,768)^T + bias
// 128x128 tile, 256 threads (4 waves, 2x2 of 64x64), K-step 64 as two
// independent BK=32 sub-tiles (R3-verified layout x2): 8 staging loads +
// 32 MFMA per wave per barrier pair (halves barrier-drain count vs BK=32).
// mode 0: bf16 store; mode 2: f32 = resid + gamma*(acc+bias);
// mode 3: f32 store, dual bias split at nsplit; else f32 store.
// ---------------------------------------------------------------------------
__global__ __launch_bounds__(256) void mfma_gemm(
    const bf16*  __restrict__ A,
    const bf16*  __restrict__ Bt,
    const float* __restrict__ bias,
    void*        __restrict__ C,
    const float* __restrict__ resid,
    const float* __restrict__ gamma,
    const float* __restrict__ bias2,
    int M, int N, int mode, int nsplit)
{
    __shared__ __align__(16) char lds[32768];   // 2 sub-tiles x (A 8K + B 8K)

    int tid  = threadIdx.x;
    int lane = tid & 63;
    int bm = blockIdx.y * 128, bn = blockIdx.x * 128;
    int wave = tid >> 6;
    int wr = (wave & 1) * 64, wc = (wave >> 1) * 64;

    ffrag acc[4][4] = {};

    // staging (per sub-tile, R3 layout): 512 chunks of 16B; thread covers
    // chunks tid, tid+256. chunk c: row = c>>2, K-octet = (c&3)*8.
    int c0 = tid, c1 = tid + 256;
    int r0 = c0 >> 2, kb0 = (c0 & 3) * 8;
    int r1 = c1 >> 2, kb1 = (c1 & 3) * 8;
    int ra0 = min(bm + r0, M - 1), ra1 = min(bm + r1, M - 1);
    const bf16* gA0 = A  + (size_t)ra0 * K_DIM + kb0;
    const bf16* gA1 = A  + (size_t)ra1 * K_DIM + kb1;
    const bf16* gB0 = Bt + (size_t)(bn + r0) * K_DIM + kb0;
    const bf16* gB1 = Bt + (size_t)(bn + r1) * K_DIM + kb1;

    int mrow = lane & 15;
    int kq   = (lane >> 4) * 8;

    for (int k0 = 0; k0 < K_DIM; k0 += 64) {
        #pragma unroll
        for (int s = 0; s < 2; s++) {
            char* As = lds + s * 16384;
            char* Bs = As + 8192;
            int ko = k0 + s * 32;
            g2l16(gA0 + ko, As + c0 * 16);
            g2l16(gA1 + ko, As + c1 * 16);
            g2l16(gB0 + ko, Bs + c0 * 16);
            g2l16(gB1 + ko, Bs + c1 * 16);
        }
        __syncthreads();
        #pragma unroll
        for (int s = 0; s < 2; s++) {
            char* As = lds + s * 16384;
            char* Bs = As + 8192;
            bfrag a[4], b[4];
            #pragma unroll
            for (int t = 0; t < 4; t++) {
                a[t] = *(const bfrag*)(As + ((wr + t * 16 + mrow) * 32 + kq) * 2);
                b[t] = *(const bfrag*)(Bs + ((wc + t * 16 + mrow) * 32 + kq) * 2);
            }
            #pragma unroll
            for (int i = 0; i < 4; i++)
                #pragma unroll
                for (int j = 0; j < 4; j++)
                    acc[i][j] = __builtin_amdgcn_mfma_f32_16x16x32_bf16(
                        a[i], b[j], acc[i][j], 0, 0, 0);
        }
        __syncthreads();
    }

    // epilogue: C/D layout col = lane&15, row = (lane>>4)*4 + reg
    int q4 = (lane >> 4) * 4;
    #pragma unroll
    for (int i = 0; i < 4; i++) {
        #pragma unroll
        for (int r = 0; r < 4; r++) {
            int rg = bm + wr + i * 16 + q4 + r;
            if (rg < M) {
                #pragma unroll
                for (int j = 0; j < 4; j++) {
                    int cg = bn + wc + j * 16 + mrow;
                    if (cg < N) {
                        float bv = (mode == 3 && cg >= nsplit) ? bias2[cg - nsplit]
                                                               : bias[cg];
                        float v = acc[i][j][r] + bv;
                        size_t idx = (size_t)rg * N + cg;
                        if (mode == 0)      ((bf16*)C)[idx]  = __float2bfloat16(v);
                        else if (mode == 2) ((float*)C)[idx] = resid[idx] + gamma[cg] * v;
                        else                ((float*)C)[idx] = v;
                    }
                }
            }
        }
    }
}

// ---------------------------------------------------------------------------
// Deformable sampling, corner-parallel:
// one wave per (b,q,h) unit; lane = corner-slot (lane>>3) x channel-octet (lane&7).
// comb (B*LQ, 432) f32: cols 0..287 = offsets, 288..431 = logits.
// ---------------------------------------------------------------------------
__global__ __launch_bounds__(256) void sample_kernel(
    const bf16*  __restrict__ value,
    const float* __restrict__ comb,
    bf16*        __restrict__ attn)
{
    int unit = __builtin_amdgcn_readfirstlane((blockIdx.x << 2) + (threadIdx.x >> 6));
    int lane = threadIdx.x & 63;
    int o   = lane & 7;          // channel octet -> channels o*8..o*8+7
    int c8  = lane >> 3;         // corner slot 0..7
    int k   = c8 & 3;
    int dx  = k & 1, dy = k >> 1;
    int h  = unit % NH;
    int bq = unit / NH;
    int q  = bq & (LQ - 1);
    int b  = bq >> 12;

    const float* rowp = comb + (size_t)bq * 432;
    const float* ob = rowp + h * 24;
    const float* lg = rowp + 288 + h * 12;

    float l[12];
    float mx = -1e30f;
    #pragma unroll
    for (int i = 0; i < 12; i++) { l[i] = lg[i]; mx = fmaxf(mx, l[i]); }
    float den = 0.f;
    #pragma unroll
    for (int i = 0; i < 12; i++) { l[i] = __expf(l[i] - mx); den += l[i]; }
    float rden = 1.f / den;
    #pragma unroll
    for (int i = 0; i < 12; i++) l[i] *= rden;

    float rx = ((q & 63) + 0.5f) * (1.f / 64.f);
    float ry = ((q >> 6) + 0.5f) * (1.f / 64.f);

    float acc[8] = {0.f};

    #pragma unroll
    for (int it = 0; it < 6; it++) {
        const int wl = (it < 2) ? 112 : (it < 4 ? 56 : 28);
        const int sl = (it < 2) ? 0   : (it < 4 ? 12544 : 15680);
        int s = it * 2 + ((lane >> 5) & 1);
        float ox = ob[s * 2 + 0];
        float oy = ob[s * 2 + 1];
        float x = rx * wl + ox - 0.5f;
        float y = ry * wl + oy - 0.5f;
        float xf = floorf(x), yf = floorf(y);
        float wx = x - xf,  wy = y - yf;
        int xi = (int)xf + dx;
        int yi = (int)yf + dy;
        bool valid = ((unsigned)xi < (unsigned)wl) & ((unsigned)yi < (unsigned)wl);
        int xc = min(max(xi, 0), wl - 1);
        int yc = min(max(yi, 0), wl - 1);
        int cell = b * LIN + sl + yc * wl + xc;
        const uint4* vp = (const uint4*)(value + ((size_t)cell * NH + h) * HD + o * 8);
        uint4 v = *vp;
        float aw = (lane & 32) ? l[it * 2 + 1] : l[it * 2];
        float bw = (dx ? wx : 1.f - wx) * (dy ? wy : 1.f - wy);
        float w = valid ? aw * bw : 0.f;
        const unsigned* u = (const unsigned*)&v;
        #pragma unroll
        for (int j = 0; j < 4; j++) {
            float f0 = __uint_as_float(u[j] << 16);
            float f1 = __uint_as_float(u[j] & 0xFFFF0000u);
            acc[j * 2 + 0] = fmaf(w, f0, acc[j * 2 + 0]);
            acc[j * 2 + 1] = fmaf(w, f1, acc[j * 2 + 1]);
        }
    }

    #pragma unroll
    for (int m = 8; m <= 32; m <<= 1) {
        #pragma unroll
        for (int j = 0; j < 8; j++)
            acc[j] += __shfl_xor(acc[j], m);
    }

    if (c8 == 0) {
        union { bf16 h8[8]; uint4 u4; } r;
        #pragma unroll
        for (int j = 0; j < 8; j++) r.h8[j] = __float2bfloat16(acc[j]);
        *(uint4*)(attn + (size_t)bq * DM + h * HD + o * 8) = r.u4;
    }
}

// ---------------------------------------------------------------------------
extern "C" void kernel_launch(void* const* d_in, const int* in_sizes, int n_in,
                              void* d_out, int out_size, void* d_ws, size_t ws_size,
                              hipStream_t stream)
{
    const float* query  = (const float*)d_in[0];
    const float* feat   = (const float*)d_in[1];
    const float* ln_q_g = (const float*)d_in[2];
    const float* ln_q_b = (const float*)d_in[3];
    const float* ln_f_g = (const float*)d_in[4];
    const float* ln_f_b = (const float*)d_in[5];
    const float* W_off  = (const float*)d_in[6];
    const float* b_off  = (const float*)d_in[7];
    const float* W_attn = (const float*)d_in[8];
    const float* b_attn = (const float*)d_in[9];
    const float* W_val  = (const float*)d_in[10];
    const float* b_val  = (const float*)d_in[11];
    const float* W_out  = (const float*)d_in[12];
    const float* b_out  = (const float*)d_in[13];
    const float* gamma  = (const float*)d_in[14];
    float* out = (float*)d_out;

    char* ws = (char*)d_ws;
    char* od = (char*)d_out;
    const int M_F = BB * LIN;   // 65856
    const int M_Q = BB * LQ;    // 16384

    // ws layout (227,475,456 B proven):
    bf16*  value  = (bf16*)(ws);
    bf16*  f_ln   = (bf16*)(ws + 101154816);
    bf16*  Wt_out = (bf16*)(ws + 101154816);
    bf16*  q_ln   = (bf16*)(ws + 202309632);
    bf16*  attn   = (bf16*)(ws + 202309632);

    // d_out as scratch (dead before final GEMM):
    bf16*  Wt_val  = (bf16*)(od);
    bf16*  Wt_comb = (bf16*)(od + 1179648);
    float* comb    = (float*)(od + 2162688);

    // 1. weight cast/transpose
    cast_transpose<<<dim3(24, 24), 256, 0, stream>>>(W_val, Wt_val, 768);
    cast_transpose<<<dim3(9, 24), 256, 0, stream>>>(W_off, Wt_comb, 288);
    cast_transpose<<<dim3(7, 24), 256, 0, stream>>>(
        W_attn, Wt_comb + (size_t)288 * K_DIM, 144);

    // 2. LayerNorms (wave-per-row; rows are multiples of 4)
    ln_kernel<<<M_F / 4, 256, 0, stream>>>(feat, ln_f_g, ln_f_b, f_ln);
    ln_kernel<<<M_Q / 4, 256, 0, stream>>>(query, ln_q_g, ln_q_b, q_ln);

    // 3. value = f_ln @ W_val + b_val (bf16)
    mfma_gemm<<<dim3(6, (M_F + 127) / 128), 256, 0, stream>>>(
        f_ln, Wt_val, b_val, value, nullptr, nullptr, nullptr, M_F, DM, 0, 0);

    // 4. Wt_out into f_ln's (now dead) region
    cast_transpose<<<dim3(24, 24), 256, 0, stream>>>(W_out, Wt_out, 768);

    // 5. comb = q_ln @ [W_off | W_attn] + [b_off | b_attn] (f32, N=432)
    mfma_gemm<<<dim3(4, M_Q / 128), 256, 0, stream>>>(
        q_ln, Wt_comb, b_off, comb, nullptr, nullptr, b_attn, M_Q, 432, 3, 288);

    // 6. deformable sampling -> attn (bf16)
    sample_kernel<<<(M_Q * NH) / 4, 256, 0, stream>>>(value, comb, attn);

    // 7. out = query + gamma * (attn @ W_out + b_out)
    mfma_gemm<<<dim3(6, M_Q / 128), 256, 0, stream>>>(
        attn, Wt_out, b_out, out, query, gamma, nullptr, M_Q, DM, 2, 0);
}